// Round 1
// baseline (1337.177 us; speedup 1.0000x reference)
//
#include <hip/hip_runtime.h>
#include <cstdint>
#include <cmath>

#define DIMC   192
#define DSTATE 16
#define DCONV  4
#define DINNER 384
#define DTRANK 12
#define BSZ    4
#define HSP    64
#define WSP    64
#define LSEQ   4096          // H*W
#define NTOK   (BSZ*LSEQ)    // 16384
#define XPN    (DTRANK + 2*DSTATE)   // 44
#define XZW    (2*DINNER)    // 768

// ---------------------------------------------------------------------------
// K1: [B,C,H,W] -> LayerNorm over C -> xn [B*L, C]
// one block per (b,h) row: 64 tokens x 192 channels
// ---------------------------------------------------------------------------
__global__ __launch_bounds__(256) void ln_kernel(
    const float* __restrict__ x, const float* __restrict__ ln_w,
    const float* __restrict__ ln_b, float* __restrict__ xn) {
  __shared__ float xs[DIMC][WSP + 1];   // +1 pad: kills stride-64 bank conflict
  __shared__ float mu_s[WSP], rs_s[WSP];
  int bh = blockIdx.x;
  int b = bh >> 6, h = bh & 63;
  int tid = threadIdx.x;
  const float* xb = x + (size_t)b * DIMC * LSEQ + (size_t)h * WSP;
  for (int e = tid; e < DIMC * WSP; e += 256) {
    int c = e >> 6, w = e & 63;
    xs[c][w] = xb[(size_t)c * LSEQ + w];      // coalesced along w
  }
  __syncthreads();
  if (tid < WSP) {
    float s = 0.f, s2 = 0.f;
    for (int c = 0; c < DIMC; ++c) { float v = xs[c][tid]; s += v; s2 = fmaf(v, v, s2); }
    float mu = s * (1.f / DIMC);
    float var = s2 * (1.f / DIMC) - mu * mu;
    mu_s[tid] = mu;
    rs_s[tid] = rsqrtf(var + 1e-5f);
  }
  __syncthreads();
  float* xo = xn + (size_t)(b * LSEQ + h * WSP) * DIMC;
  for (int e = tid; e < DIMC * WSP; e += 256) {
    int w = e / DIMC, c = e % DIMC;           // c fastest -> coalesced writes
    xo[(size_t)w * DIMC + c] = (xs[c][w] - mu_s[w]) * rs_s[w] * ln_w[c] + ln_b[c];
  }
}

// ---------------------------------------------------------------------------
// K2/K4: C[M,N] = A[M,K] @ W[N,K]^T  (f32, BM=BN=64, BK=16, 4x4 microtile)
// K multiple of 16, M multiple of 64. NGUARD handles N not multiple of 64.
// ---------------------------------------------------------------------------
template<bool NGUARD>
__global__ __launch_bounds__(256) void gemm_atb(
    const float* __restrict__ A, const float* __restrict__ W,
    float* __restrict__ C, int M, int N, int K) {
  __shared__ float As[16][64];
  __shared__ float Ws[16][64];
  int bm = blockIdx.x * 64;
  int bn = blockIdx.y * 64;
  int t = threadIdx.x;
  int tx = t & 15, ty = t >> 4;
  int r = t >> 2;             // 0..63
  int cc = (t & 3) << 2;      // 0,4,8,12
  float acc[4][4] = {};
  const float* Ap = A + (size_t)(bm + r) * K + cc;
  for (int k0 = 0; k0 < K; k0 += 16) {
    float4 av = *(const float4*)(Ap + k0);
    float4 wv = make_float4(0.f, 0.f, 0.f, 0.f);
    if (!NGUARD || (bn + r) < N)
      wv = *(const float4*)(W + (size_t)(bn + r) * K + k0 + cc);
    __syncthreads();   // prior compute done before overwriting LDS
    As[cc + 0][r] = av.x; As[cc + 1][r] = av.y; As[cc + 2][r] = av.z; As[cc + 3][r] = av.w;
    Ws[cc + 0][r] = wv.x; Ws[cc + 1][r] = wv.y; Ws[cc + 2][r] = wv.z; Ws[cc + 3][r] = wv.w;
    __syncthreads();
#pragma unroll
    for (int kk = 0; kk < 16; ++kk) {
      float4 a = *(const float4*)&As[kk][tx << 2];
      float4 bv = *(const float4*)&Ws[kk][ty << 2];
      acc[0][0] = fmaf(a.x, bv.x, acc[0][0]); acc[0][1] = fmaf(a.x, bv.y, acc[0][1]);
      acc[0][2] = fmaf(a.x, bv.z, acc[0][2]); acc[0][3] = fmaf(a.x, bv.w, acc[0][3]);
      acc[1][0] = fmaf(a.y, bv.x, acc[1][0]); acc[1][1] = fmaf(a.y, bv.y, acc[1][1]);
      acc[1][2] = fmaf(a.y, bv.z, acc[1][2]); acc[1][3] = fmaf(a.y, bv.w, acc[1][3]);
      acc[2][0] = fmaf(a.z, bv.x, acc[2][0]); acc[2][1] = fmaf(a.z, bv.y, acc[2][1]);
      acc[2][2] = fmaf(a.z, bv.z, acc[2][2]); acc[2][3] = fmaf(a.z, bv.w, acc[2][3]);
      acc[3][0] = fmaf(a.w, bv.x, acc[3][0]); acc[3][1] = fmaf(a.w, bv.y, acc[3][1]);
      acc[3][2] = fmaf(a.w, bv.z, acc[3][2]); acc[3][3] = fmaf(a.w, bv.w, acc[3][3]);
    }
  }
#pragma unroll
  for (int i = 0; i < 4; ++i) {
    int m = bm + (tx << 2) + i;
#pragma unroll
    for (int j = 0; j < 4; ++j) {
      int n = bn + (ty << 2) + j;
      if (!NGUARD || n < N) C[(size_t)m * N + n] = acc[i][j];
    }
  }
}

// ---------------------------------------------------------------------------
// K3: causal depthwise conv (k=4) + bias + SiLU:  xz[:, :384] -> xm
// ---------------------------------------------------------------------------
__global__ __launch_bounds__(256) void conv_silu_kernel(
    const float* __restrict__ xz, const float* __restrict__ conv_w,
    const float* __restrict__ conv_b, float* __restrict__ xm) {
  int gid = blockIdx.x * 256 + threadIdx.x;     // < NTOK*DINNER
  int d = gid % DINNER;
  int tok = gid / DINNER;
  int l = tok & (LSEQ - 1);
  const float4 w = *(const float4*)(conv_w + d * 4);
  float acc = conv_b[d];
  const float* base = xz + (size_t)tok * XZW + d;
  if (l >= 3) acc = fmaf(w.x, base[-3 * XZW], acc);
  if (l >= 2) acc = fmaf(w.y, base[-2 * XZW], acc);
  if (l >= 1) acc = fmaf(w.z, base[-1 * XZW], acc);
  acc = fmaf(w.w, base[0], acc);
  xm[gid] = acc / (1.f + __expf(-acc));         // silu
}

// ---------------------------------------------------------------------------
// K5: dt = softplus(dbc[:, :12] @ dt_proj_w^T + dt_proj_b)  -> dtv [NTOK,384]
// block = 384 threads (one per d), 16 tokens per block
// ---------------------------------------------------------------------------
__global__ __launch_bounds__(384) void dt_kernel(
    const float* __restrict__ dbc, const float* __restrict__ dtw,
    const float* __restrict__ dtb, float* __restrict__ dtv) {
  __shared__ float ws[DINNER * 13];   // stride 13 (gcd(13,32)=1 -> no conflicts)
  int tid = threadIdx.x;
  for (int e = tid; e < DINNER * DTRANK; e += 384)
    ws[(e / DTRANK) * 13 + (e % DTRANK)] = dtw[e];
  float bias = dtb[tid];
  __syncthreads();
  int tok0 = blockIdx.x * 16;
  for (int tt = 0; tt < 16; ++tt) {
    int tok = tok0 + tt;
    const float* row = dbc + (size_t)tok * XPN;
    float v = bias;
#pragma unroll
    for (int j = 0; j < DTRANK; ++j) v = fmaf(ws[tid * 13 + j], row[j], v);
    float sp = v > 20.f ? v : log1pf(__expf(v));
    dtv[(size_t)tok * DINNER + tid] = sp;
  }
}

// ---------------------------------------------------------------------------
// K6: selective scan + D-skip + SiLU gate -> ybuf [NTOK, 384]
// grid (24 d-groups, 4 batches); block 256 = 16 d x 16 n; h in registers
// ---------------------------------------------------------------------------
__global__ __launch_bounds__(256) void scan_kernel(
    const float* __restrict__ dtv, const float* __restrict__ xm,
    const float* __restrict__ dbc, const float* __restrict__ xz,
    const float* __restrict__ A_log, const float* __restrict__ Dvec,
    float* __restrict__ ybuf) {
  __shared__ float dt_s[64][16], xm_s[64][16], bc_s[64][32], y_s[64][16];
  int d0 = blockIdx.x * 16;
  int b = blockIdx.y;
  int tid = threadIdx.x;
  int n = tid & 15, dl = tid >> 4;
  int d = d0 + dl;
  float Acoef = -__expf(A_log[d * DSTATE + n]);
  float h = 0.f;
  size_t tokbase = (size_t)b * LSEQ;
  for (int t0 = 0; t0 < LSEQ; t0 += 64) {
    __syncthreads();   // previous chunk's y_s/xm_s consumers done
#pragma unroll
    for (int it = 0; it < 4; ++it) {
      int e = tid + it * 256;
      int i = e >> 4, j = e & 15;
      size_t row = tokbase + t0 + i;
      dt_s[i][j] = dtv[row * DINNER + d0 + j];
      xm_s[i][j] = xm[row * DINNER + d0 + j];
    }
#pragma unroll
    for (int it = 0; it < 8; ++it) {
      int e = tid + it * 256;
      int i = e >> 5, j = e & 31;
      bc_s[i][j] = dbc[(tokbase + t0 + i) * XPN + DTRANK + j];   // B then C
    }
    __syncthreads();
    for (int t = 0; t < 64; ++t) {
      float dtt = dt_s[t][dl];
      float a = __expf(dtt * Acoef);
      float bx = dtt * xm_s[t][dl] * bc_s[t][n];
      h = fmaf(h, a, bx);
      float p = h * bc_s[t][16 + n];
      p += __shfl_xor(p, 1);
      p += __shfl_xor(p, 2);
      p += __shfl_xor(p, 4);
      p += __shfl_xor(p, 8);
      if (n == 0) y_s[t][dl] = p;
    }
    __syncthreads();
#pragma unroll
    for (int it = 0; it < 4; ++it) {
      int e = tid + it * 256;
      int i = e >> 4, j = e & 15;
      size_t row = tokbase + t0 + i;
      float yv = y_s[i][j] + xm_s[i][j] * Dvec[d0 + j];
      float zv = xz[row * XZW + DINNER + d0 + j];
      float g = zv / (1.f + __expf(-zv));       // silu(z)
      ybuf[row * DINNER + d0 + j] = yv * g;
    }
  }
}

// ---------------------------------------------------------------------------
// K7: out = x_residual + ybuf @ out_proj_w^T, transposed back to [B,C,H,W]
// ---------------------------------------------------------------------------
__global__ __launch_bounds__(256) void gemm_out_kernel(
    const float* __restrict__ A, const float* __restrict__ W,
    const float* __restrict__ xres, float* __restrict__ out) {
  __shared__ float As[16][64];
  __shared__ float Ws[16][64];
  const int K = DINNER, N = DIMC;
  int bm = blockIdx.x * 64;
  int bn = blockIdx.y * 64;
  int t = threadIdx.x;
  int tx = t & 15, ty = t >> 4;
  int r = t >> 2;
  int cc = (t & 3) << 2;
  float acc[4][4] = {};
  const float* Ap = A + (size_t)(bm + r) * K + cc;
  const float* Wp = W + (size_t)(bn + r) * K + cc;
  for (int k0 = 0; k0 < K; k0 += 16) {
    float4 av = *(const float4*)(Ap + k0);
    float4 wv = *(const float4*)(Wp + k0);
    __syncthreads();
    As[cc + 0][r] = av.x; As[cc + 1][r] = av.y; As[cc + 2][r] = av.z; As[cc + 3][r] = av.w;
    Ws[cc + 0][r] = wv.x; Ws[cc + 1][r] = wv.y; Ws[cc + 2][r] = wv.z; Ws[cc + 3][r] = wv.w;
    __syncthreads();
#pragma unroll
    for (int kk = 0; kk < 16; ++kk) {
      float4 a = *(const float4*)&As[kk][tx << 2];
      float4 bv = *(const float4*)&Ws[kk][ty << 2];
      acc[0][0] = fmaf(a.x, bv.x, acc[0][0]); acc[0][1] = fmaf(a.x, bv.y, acc[0][1]);
      acc[0][2] = fmaf(a.x, bv.z, acc[0][2]); acc[0][3] = fmaf(a.x, bv.w, acc[0][3]);
      acc[1][0] = fmaf(a.y, bv.x, acc[1][0]); acc[1][1] = fmaf(a.y, bv.y, acc[1][1]);
      acc[1][2] = fmaf(a.y, bv.z, acc[1][2]); acc[1][3] = fmaf(a.y, bv.w, acc[1][3]);
      acc[2][0] = fmaf(a.z, bv.x, acc[2][0]); acc[2][1] = fmaf(a.z, bv.y, acc[2][1]);
      acc[2][2] = fmaf(a.z, bv.z, acc[2][2]); acc[2][3] = fmaf(a.z, bv.w, acc[2][3]);
      acc[3][0] = fmaf(a.w, bv.x, acc[3][0]); acc[3][1] = fmaf(a.w, bv.y, acc[3][1]);
      acc[3][2] = fmaf(a.w, bv.z, acc[3][2]); acc[3][3] = fmaf(a.w, bv.w, acc[3][3]);
    }
  }
#pragma unroll
  for (int i = 0; i < 4; ++i) {
    int m = bm + (tx << 2) + i;
    int bb = m >> 12, l = m & (LSEQ - 1);
#pragma unroll
    for (int j = 0; j < 4; ++j) {
      int c = bn + (ty << 2) + j;
      size_t a = (((size_t)bb * DIMC + c) << 12) + l;
      out[a] = xres[a] + acc[i][j];
    }
  }
}

// ---------------------------------------------------------------------------
extern "C" void kernel_launch(void* const* d_in, const int* in_sizes, int n_in,
                              void* d_out, int out_size, void* d_ws, size_t ws_size,
                              hipStream_t stream) {
  const float* x        = (const float*)d_in[0];
  const float* ln_w     = (const float*)d_in[1];
  const float* ln_b     = (const float*)d_in[2];
  const float* in_proj  = (const float*)d_in[3];   // [768,192]
  const float* conv_w   = (const float*)d_in[4];   // [384,4]
  const float* conv_b   = (const float*)d_in[5];   // [384]
  const float* x_proj   = (const float*)d_in[6];   // [44,384]
  const float* dt_w     = (const float*)d_in[7];   // [384,12]
  const float* dt_b     = (const float*)d_in[8];   // [384]
  const float* A_log    = (const float*)d_in[9];   // [384,16]
  const float* Dvec     = (const float*)d_in[10];  // [384]
  const float* out_proj = (const float*)d_in[11];  // [192,384]
  float* out = (float*)d_out;

  // workspace layout (floats): total ~35.3M floats = 141.3 MB
  float* ws   = (float*)d_ws;
  float* xn   = ws;                                   // NTOK*192
  float* xz   = xn  + (size_t)NTOK * DIMC;            // NTOK*768
  float* xm   = xz  + (size_t)NTOK * XZW;             // NTOK*384
  float* dbc  = xm  + (size_t)NTOK * DINNER;          // NTOK*44
  float* dtv  = dbc + (size_t)NTOK * XPN;             // NTOK*384
  float* ybuf = dtv + (size_t)NTOK * DINNER;          // NTOK*384

  ln_kernel<<<BSZ * HSP, 256, 0, stream>>>(x, ln_w, ln_b, xn);

  gemm_atb<false><<<dim3(NTOK / 64, XZW / 64), 256, 0, stream>>>(
      xn, in_proj, xz, NTOK, XZW, DIMC);

  conv_silu_kernel<<<(NTOK * DINNER) / 256, 256, 0, stream>>>(
      xz, conv_w, conv_b, xm);

  gemm_atb<true><<<dim3(NTOK / 64, 1), 256, 0, stream>>>(
      xm, x_proj, dbc, NTOK, XPN, DINNER);

  dt_kernel<<<NTOK / 16, 384, 0, stream>>>(dbc, dt_w, dt_b, dtv);

  scan_kernel<<<dim3(DINNER / 16, BSZ), 256, 0, stream>>>(
      dtv, xm, dbc, xz, A_log, Dvec, ybuf);

  gemm_out_kernel<<<dim3(NTOK / 64, DIMC / 64), 256, 0, stream>>>(
      ybuf, out_proj, x, out);
}

// Round 2
// 353.569 us; speedup vs baseline: 3.7819x; 3.7819x over previous
//
#include <hip/hip_runtime.h>
#include <cstdint>
#include <cmath>

#define DIMC   192
#define DSTATE 16
#define DCONV  4
#define DINNER 384
#define DTRANK 12
#define BSZ    4
#define HSP    64
#define WSP    64
#define LSEQ   4096          // H*W
#define NTOK   (BSZ*LSEQ)    // 16384
#define XPN    (DTRANK + 2*DSTATE)   // 44
#define XZW    (2*DINNER)    // 768
#define LC     128                   // scan chunk length
#define NCH    (LSEQ/LC)             // 32 chunks per batch
#define NST    (BSZ*NCH*DINNER*DSTATE)  // 786432 floats per state array

// ---------------------------------------------------------------------------
// K1: [B,C,H,W] -> LayerNorm over C -> xn [B*L, C]
// ---------------------------------------------------------------------------
__global__ __launch_bounds__(256) void ln_kernel(
    const float* __restrict__ x, const float* __restrict__ ln_w,
    const float* __restrict__ ln_b, float* __restrict__ xn) {
  __shared__ float xs[DIMC][WSP + 1];
  __shared__ float mu_s[WSP], rs_s[WSP];
  int bh = blockIdx.x;
  int b = bh >> 6, h = bh & 63;
  int tid = threadIdx.x;
  const float* xb = x + (size_t)b * DIMC * LSEQ + (size_t)h * WSP;
  for (int e = tid; e < DIMC * WSP; e += 256) {
    int c = e >> 6, w = e & 63;
    xs[c][w] = xb[(size_t)c * LSEQ + w];
  }
  __syncthreads();
  if (tid < WSP) {
    float s = 0.f, s2 = 0.f;
    for (int c = 0; c < DIMC; ++c) { float v = xs[c][tid]; s += v; s2 = fmaf(v, v, s2); }
    float mu = s * (1.f / DIMC);
    float var = s2 * (1.f / DIMC) - mu * mu;
    mu_s[tid] = mu;
    rs_s[tid] = rsqrtf(var + 1e-5f);
  }
  __syncthreads();
  float* xo = xn + (size_t)(b * LSEQ + h * WSP) * DIMC;
  for (int e = tid; e < DIMC * WSP; e += 256) {
    int w = e / DIMC, c = e % DIMC;
    xo[(size_t)w * DIMC + c] = (xs[c][w] - mu_s[w]) * rs_s[w] * ln_w[c] + ln_b[c];
  }
}

// ---------------------------------------------------------------------------
// K2/K4: C[M,N] = A[M,K] @ W[N,K]^T  (f32, BM=BN=64, BK=16, 4x4 microtile)
// ---------------------------------------------------------------------------
template<bool NGUARD>
__global__ __launch_bounds__(256) void gemm_atb(
    const float* __restrict__ A, const float* __restrict__ W,
    float* __restrict__ C, int M, int N, int K) {
  __shared__ float As[16][64];
  __shared__ float Ws[16][64];
  int bm = blockIdx.x * 64;
  int bn = blockIdx.y * 64;
  int t = threadIdx.x;
  int tx = t & 15, ty = t >> 4;
  int r = t >> 2;
  int cc = (t & 3) << 2;
  float acc[4][4] = {};
  const float* Ap = A + (size_t)(bm + r) * K + cc;
  for (int k0 = 0; k0 < K; k0 += 16) {
    float4 av = *(const float4*)(Ap + k0);
    float4 wv = make_float4(0.f, 0.f, 0.f, 0.f);
    if (!NGUARD || (bn + r) < N)
      wv = *(const float4*)(W + (size_t)(bn + r) * K + k0 + cc);
    __syncthreads();
    As[cc + 0][r] = av.x; As[cc + 1][r] = av.y; As[cc + 2][r] = av.z; As[cc + 3][r] = av.w;
    Ws[cc + 0][r] = wv.x; Ws[cc + 1][r] = wv.y; Ws[cc + 2][r] = wv.z; Ws[cc + 3][r] = wv.w;
    __syncthreads();
#pragma unroll
    for (int kk = 0; kk < 16; ++kk) {
      float4 a = *(const float4*)&As[kk][tx << 2];
      float4 bv = *(const float4*)&Ws[kk][ty << 2];
      acc[0][0] = fmaf(a.x, bv.x, acc[0][0]); acc[0][1] = fmaf(a.x, bv.y, acc[0][1]);
      acc[0][2] = fmaf(a.x, bv.z, acc[0][2]); acc[0][3] = fmaf(a.x, bv.w, acc[0][3]);
      acc[1][0] = fmaf(a.y, bv.x, acc[1][0]); acc[1][1] = fmaf(a.y, bv.y, acc[1][1]);
      acc[1][2] = fmaf(a.y, bv.z, acc[1][2]); acc[1][3] = fmaf(a.y, bv.w, acc[1][3]);
      acc[2][0] = fmaf(a.z, bv.x, acc[2][0]); acc[2][1] = fmaf(a.z, bv.y, acc[2][1]);
      acc[2][2] = fmaf(a.z, bv.z, acc[2][2]); acc[2][3] = fmaf(a.z, bv.w, acc[2][3]);
      acc[3][0] = fmaf(a.w, bv.x, acc[3][0]); acc[3][1] = fmaf(a.w, bv.y, acc[3][1]);
      acc[3][2] = fmaf(a.w, bv.z, acc[3][2]); acc[3][3] = fmaf(a.w, bv.w, acc[3][3]);
    }
  }
#pragma unroll
  for (int i = 0; i < 4; ++i) {
    int m = bm + (tx << 2) + i;
#pragma unroll
    for (int j = 0; j < 4; ++j) {
      int n = bn + (ty << 2) + j;
      if (!NGUARD || n < N) C[(size_t)m * N + n] = acc[i][j];
    }
  }
}

// ---------------------------------------------------------------------------
// K3: causal depthwise conv (k=4) + bias + SiLU
// ---------------------------------------------------------------------------
__global__ __launch_bounds__(256) void conv_silu_kernel(
    const float* __restrict__ xz, const float* __restrict__ conv_w,
    const float* __restrict__ conv_b, float* __restrict__ xm) {
  int gid = blockIdx.x * 256 + threadIdx.x;
  int d = gid % DINNER;
  int tok = gid / DINNER;
  int l = tok & (LSEQ - 1);
  const float4 w = *(const float4*)(conv_w + d * 4);
  float acc = conv_b[d];
  const float* base = xz + (size_t)tok * XZW + d;
  if (l >= 3) acc = fmaf(w.x, base[-3 * XZW], acc);
  if (l >= 2) acc = fmaf(w.y, base[-2 * XZW], acc);
  if (l >= 1) acc = fmaf(w.z, base[-1 * XZW], acc);
  acc = fmaf(w.w, base[0], acc);
  xm[gid] = acc / (1.f + __expf(-acc));
}

// ---------------------------------------------------------------------------
// K5: dt = softplus(dbc[:, :12] @ dt_proj_w^T + dt_proj_b)
// ---------------------------------------------------------------------------
__global__ __launch_bounds__(384) void dt_kernel(
    const float* __restrict__ dbc, const float* __restrict__ dtw,
    const float* __restrict__ dtb, float* __restrict__ dtv) {
  __shared__ float ws[DINNER * 13];
  int tid = threadIdx.x;
  for (int e = tid; e < DINNER * DTRANK; e += 384)
    ws[(e / DTRANK) * 13 + (e % DTRANK)] = dtw[e];
  float bias = dtb[tid];
  __syncthreads();
  int tok0 = blockIdx.x * 16;
  for (int tt = 0; tt < 16; ++tt) {
    int tok = tok0 + tt;
    const float* row = dbc + (size_t)tok * XPN;
    float v = bias;
#pragma unroll
    for (int j = 0; j < DTRANK; ++j) v = fmaf(ws[tid * 13 + j], row[j], v);
    float sp = v > 20.f ? v : log1pf(__expf(v));
    dtv[(size_t)tok * DINNER + tid] = sp;
  }
}

// ---------------------------------------------------------------------------
// K6a: chunk-local scan: h_end (from h0=0) and decay product P per chunk.
// grid (24 dgroups, 32 chunks, 4 batches); block 256 = 16d x 16n
// ---------------------------------------------------------------------------
__global__ __launch_bounds__(256) void scan_part1(
    const float* __restrict__ dtv, const float* __restrict__ xm,
    const float* __restrict__ dbc, const float* __restrict__ A_log,
    float* __restrict__ hend, float* __restrict__ pprod) {
  __shared__ float dt_s[LC][16], xm_s[LC][16], b_s[LC][16];
  int g = blockIdx.x, c = blockIdx.y, b = blockIdx.z;
  int d0 = g * 16;
  int tid = threadIdx.x;
  int n = tid & 15, dl = tid >> 4;
  int d = d0 + dl;
  float Acoef = -__expf(A_log[d * DSTATE + n]);
  size_t rowbase = (size_t)b * LSEQ + (size_t)c * LC;
#pragma unroll
  for (int it = 0; it < 8; ++it) {
    int e = tid + it * 256;
    int i = e >> 4, j = e & 15;
    size_t row = rowbase + i;
    dt_s[i][j] = dtv[row * DINNER + d0 + j];
    xm_s[i][j] = xm[row * DINNER + d0 + j];
    b_s[i][j]  = dbc[row * XPN + DTRANK + j];   // B part
  }
  __syncthreads();
  float h = 0.f, pa = 1.f;
  for (int t = 0; t < LC; ++t) {
    float dtt = dt_s[t][dl];
    float a = __expf(dtt * Acoef);
    pa *= a;
    h = fmaf(h, a, dtt * xm_s[t][dl] * b_s[t][n]);
  }
  size_t idx = (((size_t)(b * NCH + c) * DINNER) + d) * DSTATE + n;
  hend[idx] = h;
  pprod[idx] = pa;
}

// ---------------------------------------------------------------------------
// K6b: sequential chunk-boundary propagation: H_in[c] = state entering chunk c
// grid (24 dgroups, 4 batches); 32 sequential chunk steps
// ---------------------------------------------------------------------------
__global__ __launch_bounds__(256) void scan_part2(
    const float* __restrict__ hend, const float* __restrict__ pprod,
    float* __restrict__ hin) {
  int g = blockIdx.x, b = blockIdx.y;
  int tid = threadIdx.x;
  int d = g * 16 + (tid >> 4), n = tid & 15;
  float H = 0.f;
  for (int c = 0; c < NCH; ++c) {
    size_t idx = (((size_t)(b * NCH + c) * DINNER) + d) * DSTATE + n;
    hin[idx] = H;
    H = fmaf(pprod[idx], H, hend[idx]);
  }
}

// ---------------------------------------------------------------------------
// K6c: chunk scan seeded with exact H_in -> y, fused D-skip + SiLU gate
// grid (24 dgroups, 32 chunks, 4 batches); block 256 = 16d x 16n
// ---------------------------------------------------------------------------
__global__ __launch_bounds__(256) void scan_part3(
    const float* __restrict__ dtv, const float* __restrict__ xm,
    const float* __restrict__ dbc, const float* __restrict__ xz,
    const float* __restrict__ A_log, const float* __restrict__ Dvec,
    const float* __restrict__ hin, float* __restrict__ ybuf) {
  __shared__ float dt_s[LC][16], xm_s[LC][16], bc_s[LC][32], y_s[LC][16];
  int g = blockIdx.x, c = blockIdx.y, b = blockIdx.z;
  int d0 = g * 16;
  int tid = threadIdx.x;
  int n = tid & 15, dl = tid >> 4;
  int d = d0 + dl;
  float Acoef = -__expf(A_log[d * DSTATE + n]);
  size_t rowbase = (size_t)b * LSEQ + (size_t)c * LC;
#pragma unroll
  for (int it = 0; it < 8; ++it) {
    int e = tid + it * 256;
    int i = e >> 4, j = e & 15;
    size_t row = rowbase + i;
    dt_s[i][j] = dtv[row * DINNER + d0 + j];
    xm_s[i][j] = xm[row * DINNER + d0 + j];
  }
#pragma unroll
  for (int it = 0; it < 16; ++it) {
    int e = tid + it * 256;
    int i = e >> 5, j = e & 31;
    bc_s[i][j] = dbc[(rowbase + i) * XPN + DTRANK + j];   // B then C
  }
  size_t sidx = (((size_t)(b * NCH + c) * DINNER) + d) * DSTATE + n;
  float h = hin[sidx];
  __syncthreads();
  for (int t = 0; t < LC; ++t) {
    float dtt = dt_s[t][dl];
    float a = __expf(dtt * Acoef);
    h = fmaf(h, a, dtt * xm_s[t][dl] * bc_s[t][n]);
    float p = h * bc_s[t][16 + n];
    p += __shfl_xor(p, 1);
    p += __shfl_xor(p, 2);
    p += __shfl_xor(p, 4);
    p += __shfl_xor(p, 8);
    if (n == 0) y_s[t][dl] = p;
  }
  __syncthreads();
#pragma unroll
  for (int it = 0; it < 8; ++it) {
    int e = tid + it * 256;
    int i = e >> 4, j = e & 15;
    size_t row = rowbase + i;
    float yv = y_s[i][j] + xm_s[i][j] * Dvec[d0 + j];
    float zv = xz[row * XZW + DINNER + d0 + j];
    float gt = zv / (1.f + __expf(-zv));
    ybuf[row * DINNER + d0 + j] = yv * gt;
  }
}

// ---------------------------------------------------------------------------
// K7: out = x_residual + ybuf @ out_proj_w^T, transposed back to [B,C,H,W]
// ---------------------------------------------------------------------------
__global__ __launch_bounds__(256) void gemm_out_kernel(
    const float* __restrict__ A, const float* __restrict__ W,
    const float* __restrict__ xres, float* __restrict__ out) {
  __shared__ float As[16][64];
  __shared__ float Ws[16][64];
  const int K = DINNER, N = DIMC;
  int bm = blockIdx.x * 64;
  int bn = blockIdx.y * 64;
  int t = threadIdx.x;
  int tx = t & 15, ty = t >> 4;
  int r = t >> 2;
  int cc = (t & 3) << 2;
  float acc[4][4] = {};
  const float* Ap = A + (size_t)(bm + r) * K + cc;
  const float* Wp = W + (size_t)(bn + r) * K + cc;
  for (int k0 = 0; k0 < K; k0 += 16) {
    float4 av = *(const float4*)(Ap + k0);
    float4 wv = *(const float4*)(Wp + k0);
    __syncthreads();
    As[cc + 0][r] = av.x; As[cc + 1][r] = av.y; As[cc + 2][r] = av.z; As[cc + 3][r] = av.w;
    Ws[cc + 0][r] = wv.x; Ws[cc + 1][r] = wv.y; Ws[cc + 2][r] = wv.z; Ws[cc + 3][r] = wv.w;
    __syncthreads();
#pragma unroll
    for (int kk = 0; kk < 16; ++kk) {
      float4 a = *(const float4*)&As[kk][tx << 2];
      float4 bv = *(const float4*)&Ws[kk][ty << 2];
      acc[0][0] = fmaf(a.x, bv.x, acc[0][0]); acc[0][1] = fmaf(a.x, bv.y, acc[0][1]);
      acc[0][2] = fmaf(a.x, bv.z, acc[0][2]); acc[0][3] = fmaf(a.x, bv.w, acc[0][3]);
      acc[1][0] = fmaf(a.y, bv.x, acc[1][0]); acc[1][1] = fmaf(a.y, bv.y, acc[1][1]);
      acc[1][2] = fmaf(a.y, bv.z, acc[1][2]); acc[1][3] = fmaf(a.y, bv.w, acc[1][3]);
      acc[2][0] = fmaf(a.z, bv.x, acc[2][0]); acc[2][1] = fmaf(a.z, bv.y, acc[2][1]);
      acc[2][2] = fmaf(a.z, bv.z, acc[2][2]); acc[2][3] = fmaf(a.z, bv.w, acc[2][3]);
      acc[3][0] = fmaf(a.w, bv.x, acc[3][0]); acc[3][1] = fmaf(a.w, bv.y, acc[3][1]);
      acc[3][2] = fmaf(a.w, bv.z, acc[3][2]); acc[3][3] = fmaf(a.w, bv.w, acc[3][3]);
    }
  }
#pragma unroll
  for (int i = 0; i < 4; ++i) {
    int m = bm + (tx << 2) + i;
    int bb = m >> 12, l = m & (LSEQ - 1);
#pragma unroll
    for (int j = 0; j < 4; ++j) {
      int cch = bn + (ty << 2) + j;
      size_t a = (((size_t)bb * DIMC + cch) << 12) + l;
      out[a] = xres[a] + acc[i][j];
    }
  }
}

// ---------------------------------------------------------------------------
extern "C" void kernel_launch(void* const* d_in, const int* in_sizes, int n_in,
                              void* d_out, int out_size, void* d_ws, size_t ws_size,
                              hipStream_t stream) {
  const float* x        = (const float*)d_in[0];
  const float* ln_w     = (const float*)d_in[1];
  const float* ln_b     = (const float*)d_in[2];
  const float* in_proj  = (const float*)d_in[3];   // [768,192]
  const float* conv_w   = (const float*)d_in[4];   // [384,4]
  const float* conv_b   = (const float*)d_in[5];   // [384]
  const float* x_proj   = (const float*)d_in[6];   // [44,384]
  const float* dt_w     = (const float*)d_in[7];   // [384,12]
  const float* dt_b     = (const float*)d_in[8];   // [384]
  const float* A_log    = (const float*)d_in[9];   // [384,16]
  const float* Dvec     = (const float*)d_in[10];  // [384]
  const float* out_proj = (const float*)d_in[11];  // [192,384]
  float* out = (float*)d_out;

  // workspace layout (floats): same total as round 1 (~141 MB)
  float* ws   = (float*)d_ws;
  float* xn   = ws;                                   // NTOK*192 (dead after in_proj)
  float* xz   = xn  + (size_t)NTOK * DIMC;            // NTOK*768
  float* xm   = xz  + (size_t)NTOK * XZW;             // NTOK*384
  float* dbc  = xm  + (size_t)NTOK * DINNER;          // NTOK*44
  float* dtv  = dbc + (size_t)NTOK * XPN;             // NTOK*384
  float* ybuf = dtv + (size_t)NTOK * DINNER;          // NTOK*384
  // scan chunk-state arrays alias xn (3*NST = 2.36M floats < NTOK*192 = 3.14M)
  float* hend  = xn;
  float* pprod = xn + (size_t)NST;
  float* hin   = xn + 2 * (size_t)NST;

  ln_kernel<<<BSZ * HSP, 256, 0, stream>>>(x, ln_w, ln_b, xn);

  gemm_atb<false><<<dim3(NTOK / 64, XZW / 64), 256, 0, stream>>>(
      xn, in_proj, xz, NTOK, XZW, DIMC);

  conv_silu_kernel<<<(NTOK * DINNER) / 256, 256, 0, stream>>>(
      xz, conv_w, conv_b, xm);

  gemm_atb<true><<<dim3(NTOK / 64, 1), 256, 0, stream>>>(
      xm, x_proj, dbc, NTOK, XPN, DINNER);

  dt_kernel<<<NTOK / 16, 384, 0, stream>>>(dbc, dt_w, dt_b, dtv);

  scan_part1<<<dim3(DINNER / 16, NCH, BSZ), 256, 0, stream>>>(
      dtv, xm, dbc, A_log, hend, pprod);
  scan_part2<<<dim3(DINNER / 16, BSZ), 256, 0, stream>>>(hend, pprod, hin);
  scan_part3<<<dim3(DINNER / 16, NCH, BSZ), 256, 0, stream>>>(
      dtv, xm, dbc, xz, A_log, Dvec, hin, ybuf);

  gemm_out_kernel<<<dim3(NTOK / 64, DIMC / 64), 256, 0, stream>>>(
      ybuf, out_proj, x, out);
}

// Round 3
// 198.288 us; speedup vs baseline: 6.7436x; 1.7831x over previous
//
#include <hip/hip_runtime.h>
#include <hip/hip_bf16.h>
#include <cstdint>
#include <cmath>

#define DIMC   192
#define DSTATE 16
#define DCONV  4
#define DINNER 384
#define DTRANK 12
#define BSZ    4
#define HSP    64
#define WSP    64
#define LSEQ   4096
#define NTOK   (BSZ*LSEQ)            // 16384
#define XPN    (DTRANK + 2*DSTATE)   // 44
#define XZW    (2*DINNER)            // 768
#define LC2    64                    // scan chunk length
#define NCH2   (LSEQ/LC2)            // 64 chunks per batch
#define NST2   ((size_t)BSZ*NCH2*DINNER*DSTATE)  // 1,572,864 floats per state array

typedef unsigned short ushortT;
using short8 = __attribute__((ext_vector_type(8))) short;
using f32x4  = __attribute__((ext_vector_type(4))) float;

// ---------------------------------------------------------------------------
// K0: weight conversion f32 -> bf16.  [in_proj 768x192][x_proj padded 48x384][out_proj 192x384]
// ---------------------------------------------------------------------------
__global__ __launch_bounds__(256) void wcvt_kernel(
    const float* __restrict__ w_in, const float* __restrict__ w_x,
    const float* __restrict__ w_out, __hip_bfloat16* __restrict__ wbf) {
  int gid = blockIdx.x * 256 + threadIdx.x;   // < 239616
  float v;
  if (gid < 147456) {
    v = w_in[gid];
  } else if (gid < 147456 + 18432) {
    int e = gid - 147456;
    int r = e / DINNER, c = e % DINNER;
    v = (r < XPN - DTRANK + 12) && (r < 44) ? w_x[r * DINNER + c] : 0.f;  // rows 44..47 zero
  } else {
    v = w_out[gid - 147456 - 18432];
  }
  wbf[gid] = __float2bfloat16(v);
}

// ---------------------------------------------------------------------------
// K1: [B,C,H,W] -> LayerNorm over C -> xn_bf16 [B*L, C]
// ---------------------------------------------------------------------------
__global__ __launch_bounds__(256) void ln_kernel(
    const float* __restrict__ x, const float* __restrict__ ln_w,
    const float* __restrict__ ln_b, __hip_bfloat16* __restrict__ xn) {
  __shared__ float xs[DIMC][WSP + 1];
  __shared__ float mu_s[WSP], rs_s[WSP];
  int bh = blockIdx.x;
  int b = bh >> 6, h = bh & 63;
  int tid = threadIdx.x;
  const float* xb = x + (size_t)b * DIMC * LSEQ + (size_t)h * WSP;
  for (int e = tid; e < DIMC * WSP; e += 256) {
    int c = e >> 6, w = e & 63;
    xs[c][w] = xb[(size_t)c * LSEQ + w];
  }
  __syncthreads();
  if (tid < WSP) {
    float s = 0.f, s2 = 0.f;
    for (int c = 0; c < DIMC; ++c) { float v = xs[c][tid]; s += v; s2 = fmaf(v, v, s2); }
    float mu = s * (1.f / DIMC);
    float var = s2 * (1.f / DIMC) - mu * mu;
    mu_s[tid] = mu;
    rs_s[tid] = rsqrtf(var + 1e-5f);
  }
  __syncthreads();
  __hip_bfloat16* xo = xn + (size_t)(b * LSEQ + h * WSP) * DIMC;
  for (int e = tid; e < DIMC * WSP; e += 256) {
    int w = e / DIMC, c = e % DIMC;
    xo[(size_t)w * DIMC + c] =
        __float2bfloat16((xs[c][w] - mu_s[w]) * rs_s[w] * ln_w[c] + ln_b[c]);
  }
}

// ---------------------------------------------------------------------------
// bf16 MFMA GEMM: C[M,N] = A[M,K] @ B[N,K]^T   (both row-major [dim][K] bf16)
// 16x16x32 mfma; BK=64; BM = WM*FM*16, BN = WN*FN*16; 256 threads = 4 waves.
// EPI 0: C[m*ldc+n] (guard n<Nreal).  EPI 1: per-batch residual+store to [B,C,L].
// ---------------------------------------------------------------------------
template<int WM, int WN, int FM, int FN, int EPI>
__global__ __launch_bounds__(256) void gemm_bf16(
    const ushortT* __restrict__ A, const ushortT* __restrict__ B,
    float* __restrict__ C, const float* __restrict__ xres,
    int K, int Nreal, int ldc) {
  constexpr int BM = WM * FM * 16, BN = WN * FN * 16;
  __shared__ ushortT As[BM][72];
  __shared__ ushortT Bs[BN][72];
  int bm = blockIdx.x * BM, bn = blockIdx.y * BN;
  int tid = threadIdx.x, lane = tid & 63, w = tid >> 6;
  int wm = w / WN, wn = w % WN;
  int lm = lane & 15, lk = lane >> 4;
  const ushortT* Bb = B;
  size_t zoff = 0;
  if constexpr (EPI == 1) {
    size_t zb = blockIdx.z;
    Bb = B + zb * (size_t)LSEQ * K;
    zoff = zb * (size_t)DIMC * LSEQ;
  }
  f32x4 acc[FM][FN];
#pragma unroll
  for (int mi = 0; mi < FM; ++mi)
#pragma unroll
    for (int ni = 0; ni < FN; ++ni) acc[mi][ni] = (f32x4){0.f, 0.f, 0.f, 0.f};

  for (int k0 = 0; k0 < K; k0 += 64) {
    __syncthreads();
    for (int v = tid; v < BM * 8; v += 256) {
      int row = v >> 3, c8 = v & 7;
      *(uint4*)&As[row][c8 * 8] =
          *(const uint4*)(A + (size_t)(bm + row) * K + k0 + c8 * 8);
    }
    for (int v = tid; v < BN * 8; v += 256) {
      int row = v >> 3, c8 = v & 7;
      *(uint4*)&Bs[row][c8 * 8] =
          *(const uint4*)(Bb + (size_t)(bn + row) * K + k0 + c8 * 8);
    }
    __syncthreads();
#pragma unroll
    for (int ks = 0; ks < 2; ++ks) {
      short8 af[FM], bfr[FN];
#pragma unroll
      for (int mi = 0; mi < FM; ++mi)
        af[mi] = *(const short8*)&As[wm * FM * 16 + mi * 16 + lm][ks * 32 + lk * 8];
#pragma unroll
      for (int ni = 0; ni < FN; ++ni)
        bfr[ni] = *(const short8*)&Bs[wn * FN * 16 + ni * 16 + lm][ks * 32 + lk * 8];
#pragma unroll
      for (int mi = 0; mi < FM; ++mi)
#pragma unroll
        for (int ni = 0; ni < FN; ++ni)
          acc[mi][ni] = __builtin_amdgcn_mfma_f32_16x16x32_bf16(
              af[mi], bfr[ni], acc[mi][ni], 0, 0, 0);
    }
  }
#pragma unroll
  for (int mi = 0; mi < FM; ++mi) {
#pragma unroll
    for (int ni = 0; ni < FN; ++ni) {
      int ncol = bn + wn * FN * 16 + ni * 16 + lm;
#pragma unroll
      for (int r = 0; r < 4; ++r) {
        int m = bm + wm * FM * 16 + mi * 16 + lk * 4 + r;
        if constexpr (EPI == 0) {
          if (ncol < Nreal) C[(size_t)m * ldc + ncol] = acc[mi][ni][r];
        } else {
          size_t aidx = zoff + (size_t)m * LSEQ + ncol;
          C[aidx] = xres[aidx] + acc[mi][ni][r];
        }
      }
    }
  }
}

// ---------------------------------------------------------------------------
// K3: causal depthwise conv (k=4) + bias + SiLU -> xm (f32) + xmh (bf16)
// ---------------------------------------------------------------------------
__global__ __launch_bounds__(256) void conv_silu_kernel(
    const float* __restrict__ xz, const float* __restrict__ conv_w,
    const float* __restrict__ conv_b, float* __restrict__ xm,
    __hip_bfloat16* __restrict__ xmh) {
  int gid = blockIdx.x * 256 + threadIdx.x;
  int d = gid % DINNER;
  int tok = gid / DINNER;
  int l = tok & (LSEQ - 1);
  const float4 w = *(const float4*)(conv_w + d * 4);
  float acc = conv_b[d];
  const float* base = xz + (size_t)tok * XZW + d;
  if (l >= 3) acc = fmaf(w.x, base[-3 * XZW], acc);
  if (l >= 2) acc = fmaf(w.y, base[-2 * XZW], acc);
  if (l >= 1) acc = fmaf(w.z, base[-1 * XZW], acc);
  acc = fmaf(w.w, base[0], acc);
  float s = acc / (1.f + __expf(-acc));
  xm[gid] = s;
  xmh[gid] = __float2bfloat16(s);
}

// ---------------------------------------------------------------------------
// K5: dt = softplus(dbc[:, :12] @ dt_proj_w^T + dt_proj_b)
// ---------------------------------------------------------------------------
__global__ __launch_bounds__(384) void dt_kernel(
    const float* __restrict__ dbc, const float* __restrict__ dtw,
    const float* __restrict__ dtb, float* __restrict__ dtv) {
  __shared__ float ws[DINNER * 13];
  int tid = threadIdx.x;
  for (int e = tid; e < DINNER * DTRANK; e += 384)
    ws[(e / DTRANK) * 13 + (e % DTRANK)] = dtw[e];
  float bias = dtb[tid];
  __syncthreads();
  int tok0 = blockIdx.x * 16;
  for (int tt = 0; tt < 16; ++tt) {
    int tok = tok0 + tt;
    const float* row = dbc + (size_t)tok * XPN;
    float v = bias;
#pragma unroll
    for (int j = 0; j < DTRANK; ++j) v = fmaf(ws[tid * 13 + j], row[j], v);
    float sp = v > 20.f ? v : log1pf(__expf(v));
    dtv[(size_t)tok * DINNER + tid] = sp;
  }
}

// ---------------------------------------------------------------------------
// K6a: chunk-local scan (LC=64): h_end from 0 and decay product P per chunk.
// Transposed-LDS staging; float4 tile reads.
// ---------------------------------------------------------------------------
__global__ __launch_bounds__(256) void scan_part1(
    const float* __restrict__ dtv, const float* __restrict__ xm,
    const float* __restrict__ dbc, const float* __restrict__ A_log,
    float* __restrict__ hend, float* __restrict__ pprod) {
  __shared__ float dtq[16][68], xmq[16][68], bq[16][68];
  int g = blockIdx.x, c = blockIdx.y, b = blockIdx.z;
  int d0 = g * 16, tid = threadIdx.x, n = tid & 15, dl = tid >> 4;
  float Acoef = -__expf(A_log[(d0 + dl) * DSTATE + n]);
  size_t rowbase = (size_t)b * LSEQ + (size_t)c * LC2;
#pragma unroll
  for (int it = 0; it < 4; ++it) {
    int e = tid + it * 256, i = e >> 4, j = e & 15;
    size_t row = rowbase + i;
    dtq[j][i] = dtv[row * DINNER + d0 + j];
    xmq[j][i] = xm[row * DINNER + d0 + j];
    bq[j][i]  = dbc[row * XPN + DTRANK + j];
  }
  __syncthreads();
  float h = 0.f, pa = 1.f;
  for (int t0 = 0; t0 < LC2; t0 += 16) {
    float dtr[16], xmr[16], br[16];
#pragma unroll
    for (int q = 0; q < 4; ++q) {
      *(float4*)&dtr[q * 4] = *(const float4*)&dtq[dl][t0 + q * 4];
      *(float4*)&xmr[q * 4] = *(const float4*)&xmq[dl][t0 + q * 4];
      *(float4*)&br[q * 4]  = *(const float4*)&bq[n][t0 + q * 4];
    }
#pragma unroll
    for (int i = 0; i < 16; ++i) {
      float a = __expf(dtr[i] * Acoef);
      pa *= a;
      h = fmaf(h, a, dtr[i] * xmr[i] * br[i]);
    }
  }
  size_t idx = (((size_t)(b * NCH2 + c) * DINNER) + d0 + dl) * DSTATE + n;
  hend[idx] = h;
  pprod[idx] = pa;
}

// ---------------------------------------------------------------------------
// K6b: sequential chunk-boundary propagation
// ---------------------------------------------------------------------------
__global__ __launch_bounds__(256) void scan_part2(
    const float* __restrict__ hend, const float* __restrict__ pprod,
    float* __restrict__ hin) {
  int g = blockIdx.x, b = blockIdx.y;
  int tid = threadIdx.x;
  float H = 0.f;
  size_t idx = (size_t)b * NCH2 * DINNER * DSTATE + g * 256 + tid;
  for (int c = 0; c < NCH2; ++c) {
    hin[idx] = H;
    H = fmaf(pprod[idx], H, hend[idx]);
    idx += (size_t)DINNER * DSTATE;
  }
}

// ---------------------------------------------------------------------------
// K6c: seeded chunk scan -> y; butterfly reduce-scatter (15 shfl / 16 steps);
// fused D-skip + SiLU gate; bf16 output.
// ---------------------------------------------------------------------------
__global__ __launch_bounds__(256) void scan_part3(
    const float* __restrict__ dtv, const float* __restrict__ xm,
    const float* __restrict__ dbc, const float* __restrict__ xz,
    const float* __restrict__ A_log, const float* __restrict__ Dvec,
    const float* __restrict__ hin, __hip_bfloat16* __restrict__ ybuf) {
  __shared__ float dtq[16][68], xmq[16][68], bq[16][68], cq[16][68];
  __shared__ float y_s[LC2][17];
  int g = blockIdx.x, c = blockIdx.y, b = blockIdx.z;
  int d0 = g * 16, tid = threadIdx.x, n = tid & 15, dl = tid >> 4;
  float Acoef = -__expf(A_log[(d0 + dl) * DSTATE + n]);
  size_t rowbase = (size_t)b * LSEQ + (size_t)c * LC2;
#pragma unroll
  for (int it = 0; it < 4; ++it) {
    int e = tid + it * 256, i = e >> 4, j = e & 15;
    size_t row = rowbase + i;
    dtq[j][i] = dtv[row * DINNER + d0 + j];
    xmq[j][i] = xm[row * DINNER + d0 + j];
    bq[j][i]  = dbc[row * XPN + DTRANK + j];
    cq[j][i]  = dbc[row * XPN + DTRANK + DSTATE + j];
  }
  size_t sidx = (((size_t)(b * NCH2 + c) * DINNER) + d0 + dl) * DSTATE + n;
  float h = hin[sidx];
  __syncthreads();
  for (int t0 = 0; t0 < LC2; t0 += 16) {
    float dtr[16], xmr[16], br[16], cr[16];
#pragma unroll
    for (int q = 0; q < 4; ++q) {
      *(float4*)&dtr[q * 4] = *(const float4*)&dtq[dl][t0 + q * 4];
      *(float4*)&xmr[q * 4] = *(const float4*)&xmq[dl][t0 + q * 4];
      *(float4*)&br[q * 4]  = *(const float4*)&bq[n][t0 + q * 4];
      *(float4*)&cr[q * 4]  = *(const float4*)&cq[n][t0 + q * 4];
    }
    float v[16];
#pragma unroll
    for (int i = 0; i < 16; ++i) {
      float a = __expf(dtr[i] * Acoef);
      h = fmaf(h, a, dtr[i] * xmr[i] * br[i]);
      v[i] = h * cr[i];
    }
    // butterfly reduce-scatter across the 16 n-lanes; all indices compile-time
    bool h8 = (n & 8) != 0;
#pragma unroll
    for (int j = 0; j < 8; ++j) {
      float keep = h8 ? v[j + 8] : v[j];
      float send = h8 ? v[j] : v[j + 8];
      v[j] = keep + __shfl_xor(send, 8);
    }
    bool h4 = (n & 4) != 0;
#pragma unroll
    for (int j = 0; j < 4; ++j) {
      float keep = h4 ? v[j + 4] : v[j];
      float send = h4 ? v[j] : v[j + 4];
      v[j] = keep + __shfl_xor(send, 4);
    }
    bool h2 = (n & 2) != 0;
#pragma unroll
    for (int j = 0; j < 2; ++j) {
      float keep = h2 ? v[j + 2] : v[j];
      float send = h2 ? v[j] : v[j + 2];
      v[j] = keep + __shfl_xor(send, 2);
    }
    bool h1 = (n & 1) != 0;
    {
      float keep = h1 ? v[1] : v[0];
      float send = h1 ? v[0] : v[1];
      y_s[t0 + n][dl] = keep + __shfl_xor(send, 1);
    }
  }
  __syncthreads();
#pragma unroll
  for (int it = 0; it < 4; ++it) {
    int e = tid + it * 256, i = e >> 4, j = e & 15;
    size_t row = rowbase + i;
    float yv = y_s[i][j] + xmq[j][i] * Dvec[d0 + j];
    float zv = xz[row * XZW + DINNER + d0 + j];
    float gt = zv / (1.f + __expf(-zv));
    ybuf[row * DINNER + d0 + j] = __float2bfloat16(yv * gt);
  }
}

// ---------------------------------------------------------------------------
extern "C" void kernel_launch(void* const* d_in, const int* in_sizes, int n_in,
                              void* d_out, int out_size, void* d_ws, size_t ws_size,
                              hipStream_t stream) {
  const float* x        = (const float*)d_in[0];
  const float* ln_w     = (const float*)d_in[1];
  const float* ln_b     = (const float*)d_in[2];
  const float* in_proj  = (const float*)d_in[3];   // [768,192]
  const float* conv_w   = (const float*)d_in[4];   // [384,4]
  const float* conv_b   = (const float*)d_in[5];   // [384]
  const float* x_proj   = (const float*)d_in[6];   // [44,384]
  const float* dt_w     = (const float*)d_in[7];   // [384,12]
  const float* dt_b     = (const float*)d_in[8];   // [384]
  const float* A_log    = (const float*)d_in[9];   // [384,16]
  const float* Dvec     = (const float*)d_in[10];  // [384]
  const float* out_proj = (const float*)d_in[11];  // [192,384]
  float* out = (float*)d_out;

  // workspace (floats; aliased by lifetime; total ~135.5 MB)
  float* ws = (float*)d_ws;
  float* xz   = ws;                                   // [0, 12.58M)  live d3-d9
  float* xm   = ws + 12582912;                        // 6.29M        live d4-d9
  float* sh1  = ws + 18874368;                        // 3.15M: xmh (d4-d5) / ybuf (d9-d10)
  float* dbc  = ws + 22020096;                        // 0.72M        live d5-d9
  float* dtv  = ws + 22740992;                        // 6.29M        live d6-d9
  float* sh2  = ws + 29032448;                        // 4.72M: xn_bf (d2-d3) / states (d7-d9)
  float* wbfp = ws + 33751040;                        // 0.12M: bf16 weights

  __hip_bfloat16* xmh  = (__hip_bfloat16*)sh1;
  __hip_bfloat16* ybuf = (__hip_bfloat16*)sh1;
  __hip_bfloat16* xnbf = (__hip_bfloat16*)sh2;
  float* hend  = sh2;
  float* pprod = sh2 + NST2;
  float* hin   = sh2 + 2 * NST2;
  __hip_bfloat16* wbf = (__hip_bfloat16*)wbfp;
  const ushortT* win  = (const ushortT*)wbf;            // [768][192]
  const ushortT* wx   = (const ushortT*)(wbf + 147456); // [48][384] (rows 44..47 zero)
  const ushortT* wout = (const ushortT*)(wbf + 165888); // [192][384]

  wcvt_kernel<<<936, 256, 0, stream>>>(in_proj, x_proj, out_proj, wbf);

  ln_kernel<<<BSZ * HSP, 256, 0, stream>>>(x, ln_w, ln_b, xnbf);

  // in_proj: [16384,192] x [768,192]^T -> xz f32 [16384,768]
  gemm_bf16<2, 2, 4, 2, 0><<<dim3(NTOK / 128, XZW / 64), 256, 0, stream>>>(
      (const ushortT*)xnbf, win, xz, nullptr, DIMC, XZW, XZW);

  conv_silu_kernel<<<(NTOK * DINNER) / 256, 256, 0, stream>>>(
      xz, conv_w, conv_b, xm, xmh);

  // x_proj: [16384,384] x [48,384]^T -> dbc f32 [16384,44] (guard n<44)
  gemm_bf16<4, 1, 1, 3, 0><<<dim3(NTOK / 64, 1), 256, 0, stream>>>(
      (const ushortT*)xmh, wx, dbc, nullptr, DINNER, XPN, XPN);

  dt_kernel<<<NTOK / 16, 384, 0, stream>>>(dbc, dt_w, dt_b, dtv);

  scan_part1<<<dim3(DINNER / 16, NCH2, BSZ), 256, 0, stream>>>(
      dtv, xm, dbc, A_log, hend, pprod);
  scan_part2<<<dim3(DINNER / 16, BSZ), 256, 0, stream>>>(hend, pprod, hin);
  scan_part3<<<dim3(DINNER / 16, NCH2, BSZ), 256, 0, stream>>>(
      dtv, xm, dbc, xz, A_log, Dvec, hin, ybuf);

  // out_proj (transposed orientation): A=w_out[192][384], B=ybuf[b][4096][384]
  // -> out[b][192][4096] += residual
  gemm_bf16<2, 2, 2, 4, 1><<<dim3(DIMC / 64, LSEQ / 128, BSZ), 256, 0, stream>>>(
      wout, (const ushortT*)ybuf, out, x, DINNER, LSEQ, LSEQ);
}